// Round 17
// baseline (192.862 us; speedup 1.0000x reference)
//
#include <hip/hip_runtime.h>
#include <math.h>

#define NROWS 8192
#define NF    128
#define THRF  0.004f
#define BM    128
#define BN    64
#define QN    2048
#define NITER 32          // QN / BN

typedef _Float16 f16;
typedef __attribute__((ext_vector_type(8))) _Float16 f16x8;
typedef __attribute__((ext_vector_type(4))) float f32x4;

#define MFMA16F(a, b, c) __builtin_amdgcn_mfma_f32_16x16x32_f16(a, b, c, 0, 0, 0)

// ---- LDS map: RH dbuf 2x16K | RL dbuf 2x16K | TB dbuf 2x16K | P 16K | IJ 0.5K
#define RH_OFF 0
#define RL_OFF 32768
#define TB_OFF 65536
#define PB_OFF 98304
#define IJ_OFF 114688
#define SM_BYTES 115200

typedef __attribute__((address_space(1))) const unsigned int g_u32;
typedef __attribute__((address_space(3))) unsigned int l_u32;

__device__ __forceinline__ void gload16(const void* g, void* l) {
    // wave-uniform LDS base; HW scatters lane i at base + 16*i. Global addr per-lane.
    __builtin_amdgcn_global_load_lds((g_u32*)g, (l_u32*)l, 16, 0, 0);
}

__device__ __forceinline__ unsigned short f16bits(f16 x) {
    return __builtin_bit_cast(unsigned short, x);
}

// ---------------- zero_k: graph-safe zeroing of out ----------------
__global__ __launch_bounds__(256) void zero_k(float* __restrict__ out) {
    int idx = blockIdx.x * 512 + threadIdx.x;          // f32x4 units, 2 per thread
    f32x4 z = {0.f, 0.f, 0.f, 0.f};
    reinterpret_cast<f32x4*>(out)[idx]       = z;
    reinterpret_cast<f32x4*>(out)[idx + 256] = z;
}

// ---------------- prep (merged): inv_norms + fp16 hi/lo split + transpose ----------------
__global__ __launch_bounds__(256) void prep_k(const float* __restrict__ X,
                                              float* __restrict__ inv_norm,
                                              unsigned short* __restrict__ Xh,
                                              unsigned short* __restrict__ Xl,
                                              unsigned short* __restrict__ XhT) {
    __shared__ unsigned short sT[64][136];
    const int t  = threadIdx.x;
    const int jb = blockIdx.x * 64;
    const int row = t >> 2, c0 = (t & 3) * 32;   // 4 threads/row, 32 cols each
    const int grow = jb + row;

    float v[32];
    {
        const float* src = X + (size_t)grow * NF + c0;
        #pragma unroll
        for (int k = 0; k < 8; ++k) {
            f32x4 e = *reinterpret_cast<const f32x4*>(src + 4 * k);
            v[4 * k]     = e[0]; v[4 * k + 1] = e[1];
            v[4 * k + 2] = e[2]; v[4 * k + 3] = e[3];
        }
    }
    float ss = 0.f;
    #pragma unroll
    for (int k = 0; k < 32; ++k) ss += v[k] * v[k];
    ss += __shfl_xor(ss, 1);
    ss += __shfl_xor(ss, 2);
    if ((t & 3) == 0) inv_norm[grow] = 1.0f / (sqrtf(ss) + 1e-12f);

    #pragma unroll
    for (int k = 0; k < 4; ++k) {            // 8 elems per k
        unsigned hw[4], lw[4];
        #pragma unroll
        for (int p = 0; p < 4; ++p) {
            float a = v[8 * k + 2 * p], b = v[8 * k + 2 * p + 1];
            f16 ha = (f16)a, hb = (f16)b;
            f16 la = (f16)((a - (float)ha) * 2048.0f);
            f16 lb = (f16)((b - (float)hb) * 2048.0f);
            hw[p] = (unsigned)f16bits(ha) | ((unsigned)f16bits(hb) << 16);
            lw[p] = (unsigned)f16bits(la) | ((unsigned)f16bits(lb) << 16);
        }
        uint4 h4 = {hw[0], hw[1], hw[2], hw[3]};
        uint4 l4 = {lw[0], lw[1], lw[2], lw[3]};
        *reinterpret_cast<uint4*>(Xh + (size_t)grow * NF + c0 + 8 * k) = h4;
        *reinterpret_cast<uint4*>(Xl + (size_t)grow * NF + c0 + 8 * k) = l4;
        unsigned* sp = reinterpret_cast<unsigned*>(&sT[row][c0 + 8 * k]);
        sp[0] = hw[0]; sp[1] = hw[1]; sp[2] = hw[2]; sp[3] = hw[3];
    }
    __syncthreads();
    // transpose: f = t>>1 (0..127), qh = t&1 selects 32-j half (full coverage)
    {
        int f = t >> 1, qh = t & 1;
        unsigned um[16];
        #pragma unroll
        for (int m = 0; m < 16; ++m) {
            int j = 32 * qh + 2 * m;
            um[m] = (unsigned)sT[j][f] | ((unsigned)sT[j + 1][f] << 16);
        }
        unsigned* dst = reinterpret_cast<unsigned*>(XhT + (size_t)f * NROWS + jb + 32 * qh);
        #pragma unroll
        for (int m = 0; m < 16; ++m) dst[m] = um[m];
    }
}

// ---------------- producer staging: RH + RL row tiles + f-major TB (4 waves) ----------------
// Producer wave p (0..3): 12 gload16 covering its quarter of the 48KB window.
__device__ __forceinline__ void issue_tiles_p(const unsigned short* __restrict__ Xh,
                                              const unsigned short* __restrict__ Xl,
                                              const unsigned short* __restrict__ XhT,
                                              char* SM, int p, int l, int jwin, int buf) {
    const int r16 = l >> 4, c16 = l & 15;
    #pragma unroll
    for (int u = 0; u < 4; ++u) {
        int jloc = 16 * p + 4 * u + r16;
        size_t src = (size_t)(jwin + jloc) * NF + ((c16 ^ (jloc & 15)) << 3);
        gload16(Xh + src, SM + RH_OFF + buf * 16384 + (16 * p + 4 * u) * 256);
        gload16(Xl + src, SM + RL_OFF + buf * 16384 + (16 * p + 4 * u) * 256);
    }
    const int r8 = l >> 3, c8 = l & 7;
    #pragma unroll
    for (int u = 0; u < 4; ++u) {
        int floc = 32 * p + 8 * u + r8;
        const unsigned short* src = XhT + (size_t)floc * NROWS + jwin + ((c8 ^ (floc & 7)) << 3);
        gload16(src, SM + TB_OFF + buf * 16384 + (32 * p + 8 * u) * 128);
    }
}

// ---------------- fused: producer-consumer wave specialization ----------------
// 768 threads = 12 waves = 3/SIMD. Waves 0-7: compute (R16 roles verbatim).
// Waves 8-11: pure staging producers (absorb the vmcnt drain off the compute path).
__global__ __launch_bounds__(768, 3) void fused_k(const unsigned short* __restrict__ Xh,
                                                  const unsigned short* __restrict__ Xl,
                                                  const unsigned short* __restrict__ XhT,
                                                  const float* __restrict__ inv_norm,
                                                  float* __restrict__ out) {
    __shared__ __align__(16) char SM[SM_BYTES];
    const int t = threadIdx.x;
    const int w = t >> 6, l = t & 63, l15 = l & 15, h = l >> 4;
    const bool producer = (w >= 8);
    const int im2 = (w >> 1) & 3;    // consumer: 32-row i band (0..3)
    const int jn2 = w & 1;           // consumer: GEMM1 32-j band / GEMM2 64-f band
    const int bid   = blockIdx.x;
    const int ibase = (bid >> 2) * BM;
    const int qbase = (bid & 3) * QN;

    // ---- consumer-only: Xi A-fragments (64 VGPR), pinned against remat
    f16x8 aH[2][4], aL[2][4];
    float invI2[8];
    if (!producer) {
        #pragma unroll
        for (int is = 0; is < 2; ++is) {
            const size_t ro = (size_t)(ibase + 32 * im2 + 16 * is + l15) * NF;
            #pragma unroll
            for (int ks = 0; ks < 4; ++ks) {
                aH[is][ks] = *reinterpret_cast<const f16x8*>(Xh + ro + 32 * ks + 8 * h);
                aL[is][ks] = *reinterpret_cast<const f16x8*>(Xl + ro + 32 * ks + 8 * h);
            }
        }
        #pragma unroll
        for (int is = 0; is < 2; ++is)
            #pragma unroll
            for (int ks = 0; ks < 4; ++ks) {
                asm volatile("" : "+v"(aH[is][ks]));
                asm volatile("" : "+v"(aL[is][ks]));
            }
        #pragma unroll
        for (int is = 0; is < 2; ++is)
            #pragma unroll
            for (int q = 0; q < 4; ++q) {
                float x = inv_norm[ibase + 32 * im2 + 16 * is + 4 * h + q];
                invI2[is * 4 + q] = x * x;
            }
    } else {
        // prologue: producers stage window 0 + invJ^2
        issue_tiles_p(Xh, Xl, XhT, SM, w - 8, l, qbase, 0);
        if (w == 8) {
            float x = inv_norm[qbase + l];
            ((float*)(SM + IJ_OFF))[l] = x * x;
        }
    }

    f32x4 agg[2][4];
    #pragma unroll
    for (int is = 0; is < 2; ++is)
        #pragma unroll
        for (int fs = 0; fs < 4; ++fs)
            #pragma unroll
            for (int q = 0; q < 4; ++q) agg[is][fs][q] = 0.f;

    for (int it = 0; it < NITER; ++it) {
        const int buf  = it & 1;
        const int jwin = qbase + it * BN;
        __syncthreads();      // syncA: producers drained DMA(it); consumers done reading buf^1
        if (producer) {
            if (it + 1 < NITER) {
                issue_tiles_p(Xh, Xl, XhT, SM, w - 8, l, jwin + BN, buf ^ 1);
                if (w == 8) {
                    float x = inv_norm[jwin + BN + l];
                    ((float*)(SM + IJ_OFF))[(buf ^ 1) * BN + l] = x * x;
                }
            }
        } else {
            // ---- GEMM1: S = Xi.Xj^T (hi*hi) + 2^-11*(hi*lo + lo*hi); wave = 32i x 32j
            const char* rh = SM + RH_OFF + buf * 16384;
            const char* rl = SM + RL_OFF + buf * 16384;
            f32x4 Shi[2][2], Slo[2][2];
            #pragma unroll
            for (int js = 0; js < 2; ++js)
                #pragma unroll
                for (int is = 0; is < 2; ++is)
                    #pragma unroll
                    for (int q = 0; q < 4; ++q) { Shi[js][is][q] = 0.f; Slo[js][is][q] = 0.f; }
            __builtin_amdgcn_s_setprio(1);
            #pragma unroll
            for (int ks = 0; ks < 4; ++ks) {
                #pragma unroll
                for (int js = 0; js < 2; ++js) {
                    int jl = 32 * jn2 + 16 * js + l15;
                    int boff = jl * 256 + (((4 * ks + h) ^ (jl & 15)) << 4);
                    f16x8 bh = *reinterpret_cast<const f16x8*>(rh + boff);
                    f16x8 bl = *reinterpret_cast<const f16x8*>(rl + boff);
                    #pragma unroll
                    for (int is = 0; is < 2; ++is) {
                        Shi[js][is] = MFMA16F(aH[is][ks], bh, Shi[js][is]);
                        Slo[js][is] = MFMA16F(aL[is][ks], bh, Slo[js][is]);
                        Slo[js][is] = MFMA16F(aH[is][ks], bl, Slo[js][is]);
                    }
                }
            }
            __builtin_amdgcn_s_setprio(0);

            // ---- threshold -> P[128 i][64 j] f16 {0,1}, swizzled, diagonal masked
            #pragma unroll
            for (int js = 0; js < 2; ++js) {
                int jc = 32 * jn2 + 16 * js + l15;
                float ij2 = ((const float*)(SM + IJ_OFF))[buf * BN + jc];
                #pragma unroll
                for (int is = 0; is < 2; ++is) {
                    int di = (jwin + jc) - (ibase + 32 * im2 + 16 * is + 4 * h);
                    #pragma unroll
                    for (int q = 0; q < 4; ++q) {
                        float vv = Shi[js][is][q] + Slo[js][is][q] * (1.0f / 2048.0f);
                        float t2 = vv * vv * invI2[is * 4 + q] * ij2;
                        bool p = (t2 >= THRF) && (di != q);
                        int il = 32 * im2 + 16 * is + 4 * h + q;
                        int pb = il * 128 + ((jc * 2) ^ ((il & 7) << 4));
                        *reinterpret_cast<unsigned short*>(SM + PB_OFF + pb) =
                            p ? (unsigned short)0x3C00 : (unsigned short)0;
                    }
                }
            }
        }
        // syncB (light): P visible (lgkm drained); producer DMA stays in flight
        asm volatile("s_waitcnt lgkmcnt(0)\n\ts_barrier" ::: "memory");

        if (!producer) {
            // ---- GEMM2: agg += P . Xj  (wave = 32i x 64f; A = P rows, B = f-major TB)
            const char* tbp = SM + TB_OFF + buf * 16384;
            __builtin_amdgcn_s_setprio(1);
            #pragma unroll
            for (int kj = 0; kj < 2; ++kj) {
                f16x8 pa[2];
                #pragma unroll
                for (int is = 0; is < 2; ++is) {
                    int ir = 32 * im2 + 16 * is + l15;
                    pa[is] = *reinterpret_cast<const f16x8*>(
                        SM + PB_OFF + ir * 128 + ((64 * kj + 16 * h) ^ ((ir & 7) << 4)));
                }
                #pragma unroll
                for (int fs = 0; fs < 4; ++fs) {
                    int f = 64 * jn2 + 16 * fs + l15;
                    f16x8 bt = *reinterpret_cast<const f16x8*>(
                        tbp + f * 128 + ((64 * kj + 16 * h) ^ ((f & 7) << 4)));
                    agg[0][fs] = MFMA16F(pa[0], bt, agg[0][fs]);
                    agg[1][fs] = MFMA16F(pa[1], bt, agg[1][fs]);
                }
            }
            __builtin_amdgcn_s_setprio(0);
        }
    }

    // ---- consumers accumulate partial into out via device-scope f32 atomics
    if (!producer) {
        #pragma unroll
        for (int is = 0; is < 2; ++is)
            #pragma unroll
            for (int fs = 0; fs < 4; ++fs) {
                int col = 64 * jn2 + 16 * fs + l15;
                #pragma unroll
                for (int q = 0; q < 4; ++q) {
                    int row = ibase + 32 * im2 + 16 * is + 4 * h + q;
                    atomicAdd(&out[(size_t)row * NF + col], agg[is][fs][q]);
                }
            }
    }
}

// ---------------- combine: out = relu(out @ W^T) (in place, block-local) ----------------
__global__ __launch_bounds__(256) void combine_k(const float* __restrict__ Wm,
                                                 float* __restrict__ out) {
    __shared__ float sW[NF * NF];      // 64 KB
    __shared__ float sSum[32][132];
    const int t = threadIdx.x;
    const size_t base = (size_t)blockIdx.x * 32 * NF;
    #pragma unroll
    for (int k = 0; k < 16; ++k) {
        int u4 = t + 256 * k;
        reinterpret_cast<f32x4*>(sW)[u4] = reinterpret_cast<const f32x4*>(Wm)[u4];
    }
    #pragma unroll
    for (int k = 0; k < 4; ++k) {
        int u4 = t + 256 * k;                       // f32x4 chunk index (of 1024)
        f32x4 v = reinterpret_cast<const f32x4*>(out + base)[u4];
        *reinterpret_cast<f32x4*>(&sSum[u4 >> 5][(4 * u4) & 127]) = v;
    }
    __syncthreads();
    const int r = t & 31, og = t >> 5;
    float acc[16];
    #pragma unroll
    for (int oi = 0; oi < 16; ++oi) acc[oi] = 0.f;
    #pragma unroll 8
    for (int k4 = 0; k4 < 32; ++k4) {
        f32x4 a4 = *reinterpret_cast<const f32x4*>(&sSum[r][4 * k4]);
        #pragma unroll
        for (int oi = 0; oi < 16; ++oi) {
            f32x4 w4 = *reinterpret_cast<const f32x4*>(&sW[(og * 16 + oi) * NF + 4 * k4]);
            acc[oi] += a4[0] * w4[0] + a4[1] * w4[1] + a4[2] * w4[2] + a4[3] * w4[3];
        }
    }
    #pragma unroll
    for (int o4 = 0; o4 < 4; ++o4) {
        f32x4 v4;
        #pragma unroll
        for (int e = 0; e < 4; ++e) {
            float v = acc[o4 * 4 + e];
            v4[e] = v > 0.f ? v : 0.f;
        }
        *reinterpret_cast<f32x4*>(out + base + r * NF + og * 16 + o4 * 4) = v4;
    }
}

extern "C" void kernel_launch(void* const* d_in, const int* in_sizes, int n_in,
                              void* d_out, int out_size, void* d_ws, size_t ws_size,
                              hipStream_t stream) {
    const float* feat = (const float*)d_in[0];   // [8192,128] f32
    const float* Wm   = (const float*)d_in[1];   // [128,128]  f32
    float* out        = (float*)d_out;           // [8192,128] f32

    char* ws = (char*)d_ws;
    unsigned short* Xh  = (unsigned short*)(ws);                      // 2 MB
    unsigned short* Xl  = (unsigned short*)(ws + (2u << 20));         // 2 MB
    unsigned short* XhT = (unsigned short*)(ws + (4u << 20));         // 2 MB
    float* inv_norm     = (float*)(ws + (6u << 20));                  // 32 KB

    zero_k<<<NROWS * NF / 2048, 256, 0, stream>>>(out);   // 512 blocks
    prep_k<<<NROWS / 64, 256, 0, stream>>>(feat, inv_norm, Xh, Xl, XhT);
    fused_k<<<256, 768, 0, stream>>>(Xh, Xl, XhT, inv_norm, out);
    combine_k<<<NROWS / 32, 256, 0, stream>>>(Wm, out);
}

// Round 18
// 104.406 us; speedup vs baseline: 1.8472x; 1.8472x over previous
//
#include <hip/hip_runtime.h>
#include <math.h>

#define NROWS 8192
#define NF    128
#define THRF  0.004f
#define BM    128
#define BN    64
#define QN    2048
#define NITER 32          // QN / BN

typedef _Float16 f16;
typedef __attribute__((ext_vector_type(8))) _Float16 f16x8;
typedef __attribute__((ext_vector_type(4))) float f32x4;

#define MFMA16F(a, b, c) __builtin_amdgcn_mfma_f32_16x16x32_f16(a, b, c, 0, 0, 0)

// ---- LDS map: RH dbuf 2x16K | RL dbuf 2x16K | TB dbuf 2x16K | P 16K | IJ 0.5K
#define RH_OFF 0
#define RL_OFF 32768
#define TB_OFF 65536
#define PB_OFF 98304
#define IJ_OFF 114688
#define SM_BYTES 115200

typedef __attribute__((address_space(1))) const unsigned int g_u32;
typedef __attribute__((address_space(3))) unsigned int l_u32;

__device__ __forceinline__ void gload16(const void* g, void* l) {
    // wave-uniform LDS base; HW scatters lane i at base + 16*i. Global addr per-lane.
    __builtin_amdgcn_global_load_lds((g_u32*)g, (l_u32*)l, 16, 0, 0);
}

__device__ __forceinline__ unsigned short f16bits(f16 x) {
    return __builtin_bit_cast(unsigned short, x);
}

// ---------------- prep (merged): zero out-slice + inv_norms + fp16 hi/lo split + transpose ----
__global__ __launch_bounds__(256) void prep_k(const float* __restrict__ X,
                                              float* __restrict__ inv_norm,
                                              unsigned short* __restrict__ Xh,
                                              unsigned short* __restrict__ Xl,
                                              unsigned short* __restrict__ XhT,
                                              float* __restrict__ out) {
    __shared__ unsigned short sT[64][136];
    const int t  = threadIdx.x;
    const int jb = blockIdx.x * 64;
    const int row = t >> 2, c0 = (t & 3) * 32;   // 4 threads/row, 32 cols each
    const int grow = jb + row;

    // zero this block's 64-row slice of out (graph-safe replacement for zero_k):
    // 64 rows x 128 f32 = 2048 f32x4; 8 per thread, coalesced.
    {
        f32x4 z = {0.f, 0.f, 0.f, 0.f};
        f32x4* ob = reinterpret_cast<f32x4*>(out + (size_t)jb * NF);
        #pragma unroll
        for (int k = 0; k < 8; ++k) ob[t + 256 * k] = z;
    }

    float v[32];
    {
        const float* src = X + (size_t)grow * NF + c0;
        #pragma unroll
        for (int k = 0; k < 8; ++k) {
            f32x4 e = *reinterpret_cast<const f32x4*>(src + 4 * k);
            v[4 * k]     = e[0]; v[4 * k + 1] = e[1];
            v[4 * k + 2] = e[2]; v[4 * k + 3] = e[3];
        }
    }
    float ss = 0.f;
    #pragma unroll
    for (int k = 0; k < 32; ++k) ss += v[k] * v[k];
    ss += __shfl_xor(ss, 1);
    ss += __shfl_xor(ss, 2);
    if ((t & 3) == 0) inv_norm[grow] = 1.0f / (sqrtf(ss) + 1e-12f);

    #pragma unroll
    for (int k = 0; k < 4; ++k) {            // 8 elems per k
        unsigned hw[4], lw[4];
        #pragma unroll
        for (int p = 0; p < 4; ++p) {
            float a = v[8 * k + 2 * p], b = v[8 * k + 2 * p + 1];
            f16 ha = (f16)a, hb = (f16)b;
            f16 la = (f16)((a - (float)ha) * 2048.0f);
            f16 lb = (f16)((b - (float)hb) * 2048.0f);
            hw[p] = (unsigned)f16bits(ha) | ((unsigned)f16bits(hb) << 16);
            lw[p] = (unsigned)f16bits(la) | ((unsigned)f16bits(lb) << 16);
        }
        uint4 h4 = {hw[0], hw[1], hw[2], hw[3]};
        uint4 l4 = {lw[0], lw[1], lw[2], lw[3]};
        *reinterpret_cast<uint4*>(Xh + (size_t)grow * NF + c0 + 8 * k) = h4;
        *reinterpret_cast<uint4*>(Xl + (size_t)grow * NF + c0 + 8 * k) = l4;
        unsigned* sp = reinterpret_cast<unsigned*>(&sT[row][c0 + 8 * k]);
        sp[0] = hw[0]; sp[1] = hw[1]; sp[2] = hw[2]; sp[3] = hw[3];
    }
    __syncthreads();
    // transpose: f = t>>1 (0..127), qh = t&1 selects 32-j half (full coverage)
    {
        int f = t >> 1, qh = t & 1;
        unsigned um[16];
        #pragma unroll
        for (int m = 0; m < 16; ++m) {
            int j = 32 * qh + 2 * m;
            um[m] = (unsigned)sT[j][f] | ((unsigned)sT[j + 1][f] << 16);
        }
        unsigned* dst = reinterpret_cast<unsigned*>(XhT + (size_t)f * NROWS + jb + 32 * qh);
        #pragma unroll
        for (int m = 0; m < 16; ++m) dst[m] = um[m];
    }
}

// ---------------- staging: RH + RL row tiles + f-major TB tile for window jwin ----------------
__device__ __forceinline__ void issue_tiles(const unsigned short* __restrict__ Xh,
                                            const unsigned short* __restrict__ Xl,
                                            const unsigned short* __restrict__ XhT,
                                            char* SM, int w, int l, int jwin, int buf) {
    const int r16 = l >> 4, c16 = l & 15;
    #pragma unroll
    for (int u = 0; u < 2; ++u) {
        int jloc = 8 * w + 4 * u + r16;
        size_t src = (size_t)(jwin + jloc) * NF + ((c16 ^ (jloc & 15)) << 3);
        gload16(Xh + src, SM + RH_OFF + buf * 16384 + (8 * w + 4 * u) * 256);
        gload16(Xl + src, SM + RL_OFF + buf * 16384 + (8 * w + 4 * u) * 256);
    }
    const int r8 = l >> 3, c8 = l & 7;
    #pragma unroll
    for (int u = 0; u < 2; ++u) {
        int floc = 16 * w + 8 * u + r8;
        const unsigned short* src = XhT + (size_t)floc * NROWS + jwin + ((c8 ^ (floc & 7)) << 3);
        gload16(src, SM + TB_OFF + buf * 16384 + (16 * w + 8 * u) * 128);
    }
}

// ---------------- fused: fidelity (fp16 3-pass) + threshold + aggregate ----------------
__global__ __launch_bounds__(512, 2) void fused_k(const unsigned short* __restrict__ Xh,
                                                  const unsigned short* __restrict__ Xl,
                                                  const unsigned short* __restrict__ XhT,
                                                  const float* __restrict__ inv_norm,
                                                  float* __restrict__ out) {
    __shared__ __align__(16) char SM[SM_BYTES];
    const int t = threadIdx.x;
    const int w = t >> 6, l = t & 63, l15 = l & 15, h = l >> 4;
    const int im2 = w >> 1;          // GEMM1: 32-row i band (0..3); GEMM2: same i band
    const int jn2 = w & 1;           // GEMM1: 32-col j band (0..1); GEMM2: 64-col f band
    const int bid   = blockIdx.x;
    const int ibase = (bid >> 2) * BM;
    const int qbase = (bid & 3) * QN;

    // ---- Xi A-fragments: 2 i-subtiles x 4 ks, hi + scaled-lo (64 VGPR)
    f16x8 aH[2][4], aL[2][4];
    #pragma unroll
    for (int is = 0; is < 2; ++is) {
        const size_t ro = (size_t)(ibase + 32 * im2 + 16 * is + l15) * NF;
        #pragma unroll
        for (int ks = 0; ks < 4; ++ks) {
            aH[is][ks] = *reinterpret_cast<const f16x8*>(Xh + ro + 32 * ks + 8 * h);
            aL[is][ks] = *reinterpret_cast<const f16x8*>(Xl + ro + 32 * ks + 8 * h);
        }
    }
    float invI2[8];
    #pragma unroll
    for (int is = 0; is < 2; ++is)
        #pragma unroll
        for (int q = 0; q < 4; ++q) {
            float x = inv_norm[ibase + 32 * im2 + 16 * is + 4 * h + q];
            invI2[is * 4 + q] = x * x;
        }

    // prologue: stage window 0 + invJ^2
    issue_tiles(Xh, Xl, XhT, SM, w, l, qbase, 0);
    if (t < BN) { float x = inv_norm[qbase + t]; ((float*)(SM + IJ_OFF))[t] = x * x; }

    f32x4 agg[2][4];
    #pragma unroll
    for (int is = 0; is < 2; ++is)
        #pragma unroll
        for (int fs = 0; fs < 4; ++fs)
            #pragma unroll
            for (int q = 0; q < 4; ++q) agg[is][fs][q] = 0.f;

    for (int it = 0; it < NITER; ++it) {
        const int buf  = it & 1;
        const int jwin = qbase + it * BN;
        __syncthreads();                                   // tiles(it) drained; P reads of it-1 done
        if (it + 1 < NITER) {
            issue_tiles(Xh, Xl, XhT, SM, w, l, jwin + BN, buf ^ 1);
            if (t < BN) {
                float x = inv_norm[jwin + BN + t];
                ((float*)(SM + IJ_OFF))[(buf ^ 1) * BN + t] = x * x;
            }
        }
        // ---- GEMM1: S = Xi . Xj^T (hi*hi) + 2^-11 * (hi*lo + lo*hi); wave = 32i x 32j
        const char* rh = SM + RH_OFF + buf * 16384;
        const char* rl = SM + RL_OFF + buf * 16384;
        f32x4 Shi[2][2], Slo[2][2];
        #pragma unroll
        for (int js = 0; js < 2; ++js)
            #pragma unroll
            for (int is = 0; is < 2; ++is)
                #pragma unroll
                for (int q = 0; q < 4; ++q) { Shi[js][is][q] = 0.f; Slo[js][is][q] = 0.f; }
        __builtin_amdgcn_s_setprio(1);
        #pragma unroll
        for (int ks = 0; ks < 4; ++ks) {
            #pragma unroll
            for (int js = 0; js < 2; ++js) {
                int jl = 32 * jn2 + 16 * js + l15;
                int boff = jl * 256 + (((4 * ks + h) ^ (jl & 15)) << 4);
                f16x8 bh = *reinterpret_cast<const f16x8*>(rh + boff);
                f16x8 bl = *reinterpret_cast<const f16x8*>(rl + boff);
                #pragma unroll
                for (int is = 0; is < 2; ++is) {
                    Shi[js][is] = MFMA16F(aH[is][ks], bh, Shi[js][is]);
                    Slo[js][is] = MFMA16F(aL[is][ks], bh, Slo[js][is]);
                    Slo[js][is] = MFMA16F(aH[is][ks], bl, Slo[js][is]);
                }
            }
        }
        __builtin_amdgcn_s_setprio(0);

        // ---- threshold -> P[128 i][64 j] f16 {0,1}, swizzled, diagonal masked
        #pragma unroll
        for (int js = 0; js < 2; ++js) {
            int jc = 32 * jn2 + 16 * js + l15;             // j col (this thread)
            float ij2 = ((const float*)(SM + IJ_OFF))[buf * BN + jc];
            #pragma unroll
            for (int is = 0; is < 2; ++is) {
                int di = (jwin + jc) - (ibase + 32 * im2 + 16 * is + 4 * h);
                #pragma unroll
                for (int q = 0; q < 4; ++q) {
                    float vv = Shi[js][is][q] + Slo[js][is][q] * (1.0f / 2048.0f);
                    float t2 = vv * vv * invI2[is * 4 + q] * ij2;
                    bool p = (t2 >= THRF) && (di != q);
                    int il = 32 * im2 + 16 * is + 4 * h + q;
                    int pb = il * 128 + ((jc * 2) ^ ((il & 7) << 4));
                    *reinterpret_cast<unsigned short*>(SM + PB_OFF + pb) =
                        p ? (unsigned short)0x3C00 : (unsigned short)0;
                }
            }
        }
        // light barrier: P visible (lgkm drained); prefetch DMA stays in flight
        asm volatile("s_waitcnt lgkmcnt(0)\n\ts_barrier" ::: "memory");

        // ---- GEMM2: agg += P . Xj  (wave = 32i x 64f; A = P rows, B = f-major TB)
        const char* tbp = SM + TB_OFF + buf * 16384;
        __builtin_amdgcn_s_setprio(1);
        #pragma unroll
        for (int kj = 0; kj < 2; ++kj) {
            f16x8 pa[2];
            #pragma unroll
            for (int is = 0; is < 2; ++is) {
                int ir = 32 * im2 + 16 * is + l15;
                pa[is] = *reinterpret_cast<const f16x8*>(
                    SM + PB_OFF + ir * 128 + ((64 * kj + 16 * h) ^ ((ir & 7) << 4)));
            }
            #pragma unroll
            for (int fs = 0; fs < 4; ++fs) {
                int f = 64 * jn2 + 16 * fs + l15;
                f16x8 bt = *reinterpret_cast<const f16x8*>(
                    tbp + f * 128 + ((64 * kj + 16 * h) ^ ((f & 7) << 4)));
                agg[0][fs] = MFMA16F(pa[0], bt, agg[0][fs]);
                agg[1][fs] = MFMA16F(pa[1], bt, agg[1][fs]);
            }
        }
        __builtin_amdgcn_s_setprio(0);
    }

    // ---- accumulate partial into out via device-scope f32 atomics (out zeroed by prep_k)
    #pragma unroll
    for (int is = 0; is < 2; ++is)
        #pragma unroll
        for (int fs = 0; fs < 4; ++fs) {
            int col = 64 * jn2 + 16 * fs + l15;
            #pragma unroll
            for (int q = 0; q < 4; ++q) {
                int row = ibase + 32 * im2 + 16 * is + 4 * h + q;
                atomicAdd(&out[(size_t)row * NF + col], agg[is][fs][q]);
            }
        }
}

// ---------------- combine: out = relu(out @ W^T) (in place, block-local) ----------------
__global__ __launch_bounds__(256) void combine_k(const float* __restrict__ Wm,
                                                 float* __restrict__ out) {
    __shared__ float sW[NF * NF];      // 64 KB
    __shared__ float sSum[32][132];
    const int t = threadIdx.x;
    const size_t base = (size_t)blockIdx.x * 32 * NF;
    #pragma unroll
    for (int k = 0; k < 16; ++k) {
        int u4 = t + 256 * k;
        reinterpret_cast<f32x4*>(sW)[u4] = reinterpret_cast<const f32x4*>(Wm)[u4];
    }
    #pragma unroll
    for (int k = 0; k < 4; ++k) {
        int u4 = t + 256 * k;                       // f32x4 chunk index (of 1024)
        f32x4 v = reinterpret_cast<const f32x4*>(out + base)[u4];
        *reinterpret_cast<f32x4*>(&sSum[u4 >> 5][(4 * u4) & 127]) = v;
    }
    __syncthreads();
    const int r = t & 31, og = t >> 5;
    float acc[16];
    #pragma unroll
    for (int oi = 0; oi < 16; ++oi) acc[oi] = 0.f;
    #pragma unroll 8
    for (int k4 = 0; k4 < 32; ++k4) {
        f32x4 a4 = *reinterpret_cast<const f32x4*>(&sSum[r][4 * k4]);
        #pragma unroll
        for (int oi = 0; oi < 16; ++oi) {
            f32x4 w4 = *reinterpret_cast<const f32x4*>(&sW[(og * 16 + oi) * NF + 4 * k4]);
            acc[oi] += a4[0] * w4[0] + a4[1] * w4[1] + a4[2] * w4[2] + a4[3] * w4[3];
        }
    }
    #pragma unroll
    for (int o4 = 0; o4 < 4; ++o4) {
        f32x4 v4;
        #pragma unroll
        for (int e = 0; e < 4; ++e) {
            float v = acc[o4 * 4 + e];
            v4[e] = v > 0.f ? v : 0.f;
        }
        *reinterpret_cast<f32x4*>(out + base + r * NF + og * 16 + o4 * 4) = v4;
    }
}

extern "C" void kernel_launch(void* const* d_in, const int* in_sizes, int n_in,
                              void* d_out, int out_size, void* d_ws, size_t ws_size,
                              hipStream_t stream) {
    const float* feat = (const float*)d_in[0];   // [8192,128] f32
    const float* Wm   = (const float*)d_in[1];   // [128,128]  f32
    float* out        = (float*)d_out;           // [8192,128] f32

    char* ws = (char*)d_ws;
    unsigned short* Xh  = (unsigned short*)(ws);                      // 2 MB
    unsigned short* Xl  = (unsigned short*)(ws + (2u << 20));         // 2 MB
    unsigned short* XhT = (unsigned short*)(ws + (4u << 20));         // 2 MB
    float* inv_norm     = (float*)(ws + (6u << 20));                  // 32 KB

    prep_k<<<NROWS / 64, 256, 0, stream>>>(feat, inv_norm, Xh, Xl, XhT, out);
    fused_k<<<256, 512, 0, stream>>>(Xh, Xl, XhT, inv_norm, out);
    combine_k<<<NROWS / 32, 256, 0, stream>>>(Wm, out);
}